// Round 1
// baseline (424.126 us; speedup 1.0000x reference)
//
#include <hip/hip_runtime.h>

typedef unsigned short u16;
typedef __attribute__((ext_vector_type(8))) short bf16x8;
typedef __attribute__((ext_vector_type(4))) float f32x4;
typedef __attribute__((ext_vector_type(8))) u16 u16x8;

#define GLOAD_LDS(g, s) __builtin_amdgcn_global_load_lds( \
    (const __attribute__((address_space(1))) void*)(g),   \
    (__attribute__((address_space(3))) void*)(s), 16, 0, 0)

__device__ __forceinline__ u16 f2bf(float f) {
  union { float f; unsigned u; } v; v.f = f;
  unsigned r = v.u + 0x7fffu + ((v.u >> 16) & 1u);
  return (u16)(r >> 16);
}
__device__ __forceinline__ float bf2f(u16 h) {
  union { unsigned u; float f; } v; v.u = ((unsigned)h) << 16;
  return v.f;
}

// ---- 128x128 bf16 B^T GEMM core (m97-style): 4 waves, 16x16x32 MFMA ----
// LDS tiles are [128 rows][32 k] bf16, linear (global_load_lds order).

__device__ __forceinline__ void stage_pair(const u16* gA, int lda, const u16* gB, int ldb,
                                           u16* lA, u16* lB, int wave, int lane) {
  int row = (wave << 4) + (lane >> 2);   // 16 rows per chunk, 4 lanes/row
  int kb  = (lane & 3) << 3;             // 8 bf16 = 16B per lane
  GLOAD_LDS(gA + row * lda + kb,        lA + (wave << 9));
  GLOAD_LDS(gA + (row + 64) * lda + kb, lA + ((wave + 4) << 9));
  GLOAD_LDS(gB + row * ldb + kb,        lB + (wave << 9));
  GLOAD_LDS(gB + (row + 64) * ldb + kb, lB + ((wave + 4) << 9));
}

__device__ __forceinline__ void gemm_seg(f32x4 (&acc)[4][4],
    const u16* Ag, const u16* Bg, int lda, int ldb, int nk,
    u16* As, u16* Bs, int wave, int lane) {
  __syncthreads();                                    // protect LDS from prior use
  stage_pair(Ag, lda, Bg, ldb, As, Bs, wave, lane);   // buffer 0, kt=0
  const int wr = (wave >> 1) << 6, wc = (wave & 1) << 6;
  const int rl = lane & 15, rk = (lane >> 4) << 3;
  int cur = 0;
  for (int kt = 0; kt < nk; ++kt) {
    __syncthreads();  // staging for cur complete (compiler drains vmcnt); prev reads done
    if (kt + 1 < nk)
      stage_pair(Ag + (kt + 1) * 32, lda, Bg + (kt + 1) * 32, ldb,
                 As + ((cur ^ 1) << 12), Bs + ((cur ^ 1) << 12), wave, lane);
    const u16* ab = As + (cur << 12);
    const u16* bb = Bs + (cur << 12);
    bf16x8 af[4], bfr[4];
#pragma unroll
    for (int i = 0; i < 4; i++)
      af[i]  = *(const bf16x8*)(ab + ((wr + (i << 4) + rl) << 5) + rk);
#pragma unroll
    for (int j = 0; j < 4; j++)
      bfr[j] = *(const bf16x8*)(bb + ((wc + (j << 4) + rl) << 5) + rk);
#pragma unroll
    for (int i = 0; i < 4; i++)
#pragma unroll
      for (int j = 0; j < 4; j++)
        acc[i][j] = __builtin_amdgcn_mfma_f32_16x16x32_bf16(af[i], bfr[j], acc[i][j], 0, 0, 0);
    cur ^= 1;
  }
}

// ---------------- conversion kernels ----------------
__global__ __launch_bounds__(256) void k_cvt(const float* __restrict__ in,
                                             u16* __restrict__ out, int n8) {
  int i = blockIdx.x * 256 + threadIdx.x;
  if (i >= n8) return;
  const float4* pf = (const float4*)in + (long)i * 2;
  float4 a = pf[0], b = pf[1];
  u16x8 o;
  o[0] = f2bf(a.x); o[1] = f2bf(a.y); o[2] = f2bf(a.z); o[3] = f2bf(a.w);
  o[4] = f2bf(b.x); o[5] = f2bf(b.y); o[6] = f2bf(b.z); o[7] = f2bf(b.w);
  *((u16x8*)out + i) = o;
}

struct P6 { const float* p[6]; };
struct O6 { u16* p[6]; };

__global__ __launch_bounds__(256) void k_cvt_w(P6 w, u16* __restrict__ out) {
  int z = blockIdx.y;
  int i = blockIdx.x * 256 + threadIdx.x;      // 0..32767 (512*512/8)
  const float4* pf = (const float4*)w.p[z] + (long)i * 2;
  float4 a = pf[0], b = pf[1];
  u16x8 o;
  o[0] = f2bf(a.x); o[1] = f2bf(a.y); o[2] = f2bf(a.z); o[3] = f2bf(a.w);
  o[4] = f2bf(b.x); o[5] = f2bf(b.y); o[6] = f2bf(b.z); o[7] = f2bf(b.w);
  *((u16x8*)(out + (long)z * 262144) + i) = o;
}

// ---------------- projections: out[n,e] = sum_d in[n,d] W[e,d] + b[e] ----------------
__global__ __launch_bounds__(256) void k_proj(const u16* __restrict__ Xb, const u16* __restrict__ Yb,
                                              const u16* __restrict__ Wb, P6 bias, O6 dst) {
  __shared__ u16 As[8192], Bs[8192];
  int z = blockIdx.z, bm = blockIdx.x, bn = blockIdx.y;
  int tid = threadIdx.x, wave = tid >> 6, lane = tid & 63;
  const u16* Ag = (z < 3 ? Xb : Yb) + (long)bm * 128 * 512;
  const u16* Bg = Wb + (long)z * 262144 + (long)bn * 128 * 512;
  f32x4 acc[4][4] = {};
  gemm_seg(acc, Ag, Bg, 512, 512, 16, As, Bs, wave, lane);
  const float* bi = bias.p[z];
  u16* D = dst.p[z];
  int wr = (wave >> 1) << 6, wc = (wave & 1) << 6;
  int row0 = bm * 128 + wr + ((lane >> 4) << 2);
  int col0 = bn * 128 + wc + (lane & 15);
  float bj[4];
#pragma unroll
  for (int j = 0; j < 4; j++) bj[j] = bi[col0 + (j << 4)];
#pragma unroll
  for (int i = 0; i < 4; i++)
#pragma unroll
    for (int j = 0; j < 4; j++)
#pragma unroll
      for (int r = 0; r < 4; r++)
        D[(long)(row0 + (i << 4) + r) * 512 + col0 + (j << 4)] = f2bf(acc[i][j][r] + bj[j]);
}

// ---------------- scores: S[b,n,m] = scale * sum_d Q[b,n,d] K[b,m,d] ----------------
__global__ __launch_bounds__(256) void k_s(const u16* __restrict__ Q, const u16* __restrict__ K,
                                           u16* __restrict__ S) {
  __shared__ u16 As[8192], Bs[8192];
  int b = blockIdx.z, bm = blockIdx.x, bn = blockIdx.y;
  int tid = threadIdx.x, wave = tid >> 6, lane = tid & 63;
  const u16* Ag = Q + (long)b * 1048576 + (long)bm * 128 * 512;
  const u16* Bg = K + (long)b * 1048576 + (long)bn * 128 * 512;
  f32x4 acc[4][4] = {};
  gemm_seg(acc, Ag, Bg, 512, 512, 16, As, Bs, wave, lane);
  u16* D = S + (long)b * 4194304;
  const float scale = 0.04419417382415922f;  // 1/sqrt(512)
  int wr = (wave >> 1) << 6, wc = (wave & 1) << 6;
  int row0 = bm * 128 + wr + ((lane >> 4) << 2);
  int col0 = bn * 128 + wc + (lane & 15);
#pragma unroll
  for (int i = 0; i < 4; i++)
#pragma unroll
    for (int j = 0; j < 4; j++)
#pragma unroll
      for (int r = 0; r < 4; r++)
        D[(long)(row0 + (i << 4) + r) * 2048 + col0 + (j << 4)] = f2bf(acc[i][j][r] * scale);
}

// ---------------- softmax over batch axis (8 values per (n,m)) ----------------
__global__ __launch_bounds__(256) void k_softmax(u16* __restrict__ S) {
  int idx = blockIdx.x * 256 + threadIdx.x;   // exactly 2048*256 threads, 8 positions each
  u16x8 v[8];
#pragma unroll
  for (int b = 0; b < 8; b++) v[b] = *((const u16x8*)(S + (long)b * 4194304) + idx);
#pragma unroll
  for (int j = 0; j < 8; j++) {
    float e[8], m = -1e30f;
#pragma unroll
    for (int b = 0; b < 8; b++) { e[b] = bf2f(v[b][j]); m = fmaxf(m, e[b]); }
    float s = 0.f;
#pragma unroll
    for (int b = 0; b < 8; b++) { e[b] = __expf(e[b] - m); s += e[b]; }
    float inv = 1.0f / s;
#pragma unroll
    for (int b = 0; b < 8; b++) v[b][j] = f2bf(e[b] * inv);
  }
#pragma unroll
  for (int b = 0; b < 8; b++) *((u16x8*)(S + (long)b * 4194304) + idx) = v[b];
}

// ---------------- V transpose: Vt[b,d,n] = V[b,n,d] ----------------
__global__ __launch_bounds__(256) void k_tr(const u16* __restrict__ V1, const u16* __restrict__ V2,
                                            u16* __restrict__ T1, u16* __restrict__ T2) {
  __shared__ u16 tile[64][65];
  int z = blockIdx.z;
  const u16* src = (z < 8 ? V1 : V2) + (long)(z & 7) * 1048576;
  u16*       dst = (z < 8 ? T1 : T2) + (long)(z & 7) * 1048576;
  int n0 = blockIdx.x * 64, d0 = blockIdx.y * 64;
  int t = threadIdx.x;
  int r = t >> 2, cs = (t & 3) * 16;
  const u16x8* sp = (const u16x8*)(src + (long)(n0 + r) * 512 + d0 + cs);
  u16x8 a = sp[0], b = sp[1];
#pragma unroll
  for (int jj = 0; jj < 8; jj++) { tile[r][cs + jj] = a[jj]; tile[r][cs + 8 + jj] = b[jj]; }
  __syncthreads();
  u16x8 o0, o1;
#pragma unroll
  for (int jj = 0; jj < 8; jj++) { o0[jj] = tile[cs + jj][r]; o1[jj] = tile[cs + 8 + jj][r]; }
  u16x8* op = (u16x8*)(dst + (long)(d0 + r) * 2048 + n0 + cs);
  op[0] = o0; op[1] = o1;
}

// ---------------- PV: out[b,n,d] (+)= sum_m A[b,n,m] Vt[b,d,m]  (+X+Y on mode 0) ----------------
__global__ __launch_bounds__(256) void k_pv(const u16* __restrict__ A, const u16* __restrict__ Vt,
                                            const float* __restrict__ X, const float* __restrict__ Y,
                                            float* __restrict__ out, int mode) {
  __shared__ u16 As[8192], Bs[8192];
  int b = blockIdx.z, bm = blockIdx.x, bn = blockIdx.y;
  int tid = threadIdx.x, wave = tid >> 6, lane = tid & 63;
  const u16* Ag = A + (long)b * 4194304 + (long)bm * 128 * 2048;
  const u16* Bg = Vt + (long)b * 1048576 + (long)bn * 128 * 2048;
  f32x4 acc[4][4] = {};
  gemm_seg(acc, Ag, Bg, 2048, 2048, 64, As, Bs, wave, lane);
  int wr = (wave >> 1) << 6, wc = (wave & 1) << 6;
  int row0 = bm * 128 + wr + ((lane >> 4) << 2);
  int col0 = bn * 128 + wc + (lane & 15);
  long base = (long)b * 1048576;
#pragma unroll
  for (int i = 0; i < 4; i++)
#pragma unroll
    for (int j = 0; j < 4; j++)
#pragma unroll
      for (int r = 0; r < 4; r++) {
        long idx = base + (long)(row0 + (i << 4) + r) * 512 + col0 + (j << 4);
        float v = acc[i][j][r];
        out[idx] = mode ? (out[idx] + v) : (v + X[idx] + Y[idx]);
      }
}

extern "C" void kernel_launch(void* const* d_in, const int* in_sizes, int n_in,
                              void* d_out, int out_size, void* d_ws, size_t ws_size,
                              hipStream_t stream) {
  const float* X = (const float*)d_in[0];
  const float* Y = (const float*)d_in[1];
  P6 wp, bp;
  for (int i = 0; i < 6; i++) { wp.p[i] = (const float*)d_in[2 + 2 * i]; bp.p[i] = (const float*)d_in[3 + 2 * i]; }

  const long NX = 8L * 2048 * 512;       // 8,388,608 elems per [B,N,D] tensor
  const long NS = 8L * 2048 * 2048;      // 33,554,432 elems per [B,N,N] tensor
  u16* p = (u16*)d_ws;
  u16* Xb = p;  p += NX;                  // bf16 X   (later reused as Vt1)
  u16* Yb = p;  p += NX;                  // bf16 Y   (later reused as Vt2)
  u16* Wb = p;  p += 6L * 512 * 512;      // bf16 weights
  u16* Q1 = p;  p += NX;
  u16* K1 = p;  p += NX;
  u16* Q2 = p;  p += NX;
  u16* K2 = p;  p += NX;
  u16* Sb = p;  p += NS;                  // S/A buffer (reused for S1 then S2)
  u16* V1 = Sb;                           // V temporaries overlay head of Sb
  u16* V2 = Sb + NX;
  u16* Vt1 = Xb;                          // transposed V, reuse Xb/Yb space
  u16* Vt2 = Yb;
  (void)ws_size; (void)in_sizes; (void)n_in; (void)out_size;

  dim3 T(256);
  // 1. convert inputs + weights to bf16
  k_cvt<<<dim3(4096), T, 0, stream>>>(X, Xb, (int)(NX / 8));
  k_cvt<<<dim3(4096), T, 0, stream>>>(Y, Yb, (int)(NX / 8));
  k_cvt_w<<<dim3(128, 6), T, 0, stream>>>(wp, Wb);
  // 2. six projections
  O6 dst; dst.p[0] = Q1; dst.p[1] = K1; dst.p[2] = V1; dst.p[3] = Q2; dst.p[4] = K2; dst.p[5] = V2;
  k_proj<<<dim3(128, 4, 6), T, 0, stream>>>(Xb, Yb, Wb, bp, dst);
  // 3. transpose V1->Vt1, V2->Vt2 (frees Xb/Yb which are dead now)
  k_tr<<<dim3(32, 8, 16), T, 0, stream>>>(V1, V2, Vt1, Vt2);
  // 4-6. attention 1: S1 = Q1.K2^T, softmax over b, out = A1.V2 + X + Y
  k_s<<<dim3(16, 16, 8), T, 0, stream>>>(Q1, K2, Sb);
  k_softmax<<<dim3(2048), T, 0, stream>>>(Sb);
  k_pv<<<dim3(16, 4, 8), T, 0, stream>>>(Sb, Vt2, X, Y, (float*)d_out, 0);
  // 7-9. attention 2: S2 = Q2.K1^T, softmax over b, out += A2.V1
  k_s<<<dim3(16, 16, 8), T, 0, stream>>>(Q2, K1, Sb);
  k_softmax<<<dim3(2048), T, 0, stream>>>(Sb);
  k_pv<<<dim3(16, 4, 8), T, 0, stream>>>(Sb, Vt1, X, Y, (float*)d_out, 1);
}